// Round 13
// baseline (10215.931 us; speedup 1.0000x reference)
//
#include <hip/hip_runtime.h>
#include <math.h>

#define H   256
#define TT  128
#define BT  8     // batch rows per block; grid = 256 = 1 block/CU (proven clean)
#define PP  6

typedef float v2f __attribute__((ext_vector_type(2)));

__device__ __forceinline__ float sigf(float x) { return 1.0f / (1.0f + __expf(-x)); }
__device__ __forceinline__ float tanh_fast(float x) {
    float t = __expf(-2.0f * fabsf(x));
    float r = (1.0f - t) / (1.0f + t);
    return copysignf(r, x);
}

// ---------------- pack weights (R2-verified layout, unchanged) --------------
// wbA[(k4*2+g)*256+t] = {Uz0,Ur0}[t][4k4..+3]
// wbH[k4*256+t]       = Uh0[t][4k4..+3]
// wbC[(k4*5+g)*256+t] = g=0..2: {Wz1,Wr1,Wh1}[t][4k4..+3] (ld 264, h0n cols)
//                       g=3,4 : {Uz1,Ur1}[t][4k4..+3]      (ld 256, h1 cols)
// wbD[k4*256+t]       = Uh1[t][4k4..+3]
__global__ void pack_weights(const float* __restrict__ Uz0, const float* __restrict__ Ur0, const float* __restrict__ Uh0,
                             const float* __restrict__ Wz1, const float* __restrict__ Wr1, const float* __restrict__ Wh1,
                             const float* __restrict__ Uz1, const float* __restrict__ Ur1, const float* __restrict__ Uh1,
                             float4* __restrict__ wbA, float4* __restrict__ wbH,
                             float4* __restrict__ wbC, float4* __restrict__ wbD)
{
    int idx = blockIdx.x * 256 + threadIdx.x;   // 0..147455
    if (idx < 32768) {
        int k4 = idx >> 9; int g = (idx >> 8) & 1; int t = idx & 255;
        const float* p = (g ? Ur0 : Uz0) + t * H + k4 * 4;
        wbA[idx] = make_float4(p[0], p[1], p[2], p[3]);
    } else if (idx < 49152) {
        int i = idx - 32768;
        int k4 = i >> 8, t = i & 255;
        const float* p = Uh0 + t * H + k4 * 4;
        wbH[i] = make_float4(p[0], p[1], p[2], p[3]);
    } else if (idx < 131072) {
        int i = idx - 49152;                       // 0..81919
        int k4 = i / 1280; int rem = i - k4 * 1280; int g = rem >> 8; int t = rem & 255;
        const float* p;
        if (g < 3) { const float* W = (g == 0) ? Wz1 : ((g == 1) ? Wr1 : Wh1); p = W + t * 264 + k4 * 4; }
        else       { const float* U = (g == 3) ? Uz1 : Ur1;                    p = U + t * H   + k4 * 4; }
        wbC[i] = make_float4(p[0], p[1], p[2], p[3]);
    } else if (idx < 147456) {
        int i = idx - 131072;
        int k4 = i >> 8, t = i & 255;
        const float* p = Uh1 + t * H + k4 * 4;
        wbD[i] = make_float4(p[0], p[1], p[2], p[3]);
    }
}

// ---- constants, folded (R5-verified, unchanged) ----------------------------
__global__ void pack_consts(const float* __restrict__ Wz0, const float* __restrict__ Wr0, const float* __restrict__ Wh0,
                            const float* __restrict__ Vw0, const float* __restrict__ Vb0,
                            const float* __restrict__ lz0, const float* __restrict__ lr0, const float* __restrict__ lh0,
                            const float* __restrict__ Wz1, const float* __restrict__ Wr1, const float* __restrict__ Wh1,
                            const float* __restrict__ Vw1, const float* __restrict__ Vb1,
                            const float* __restrict__ lz1, const float* __restrict__ lr1, const float* __restrict__ lh1,
                            const float* __restrict__ emb, float* __restrict__ cst)
{
    int t = threadIdx.x;
    float* A0t = cst; float* B1t = cst + 2304; float* WC = cst + 4608;
    const float* W0s[3] = {Wz0, Wr0, Wh0};
    const float* W1s[3] = {Wz1, Wr1, Wh1};
    const float* ls0[3] = {lz0, lr0, lh0};
    const float* ls1[3] = {lz1, lr1, lh1};
    for (int g = 0; g < 3; ++g) {
        WC[g * H + t] = W0s[g][t * 9];
        float L0g = 0.05f + 0.45f * sigf(ls0[g][t]);
        float L1g = 0.05f + 0.45f * sigf(ls1[g][t]);
        for (int c = 0; c < 3; ++c) {
            float s0 = 0.f, s1 = 0.f, i0 = Vb0[t], i1 = Vb1[t];
            for (int e = 0; e < 8; ++e) {
                float em = emb[c * 8 + e];
                s0 += W0s[g][t * 9 + 1 + e]     * em;
                s1 += W1s[g][t * 264 + 256 + e] * em;
                i0 += Vw0[t * 8 + e] * em;
                i1 += Vw1[t * 8 + e] * em;
            }
            A0t[(g * 3 + c) * H + t] = s0 + L0g * i0;
            B1t[(g * 3 + c) * H + t] = s1 + L1g * i1;
        }
    }
}

// -------- persistent scan: R12 + deeper rings (A16/B16/C8/D4) ---------------
// 256 thr, thread t owns hidden unit t for all 8 rows, grid 256 (1 block/CU,
// 1 wave/SIMD -> VGPR budget ~512; launch_bounds(256,1) licenses it).
__global__ __launch_bounds__(256, 1) void trs_scan(
    const float* __restrict__ x,
    const float4* __restrict__ wbA, const float4* __restrict__ wbH,
    const float4* __restrict__ wbC, const float4* __restrict__ wbD,
    const float* __restrict__ cst, const float* __restrict__ fcw, const float* __restrict__ fcb,
    float* __restrict__ out)
{
    // +1 padding row: k4=63 h-prefetch over-reads stay in-bounds
    __shared__ __align__(16) float h0s[BT + 1][H];
    __shared__ __align__(16) float h1s[BT + 1][H];
    __shared__ __align__(16) float rh0[BT + 1][H];
    __shared__ __align__(16) float rh1[BT + 1][H];
    __shared__ float xm[BT][TT];
    __shared__ unsigned char xcl[BT][TT];

    const int t  = threadIdx.x;
    const int r0 = blockIdx.x * BT;

    const float* A0t = cst; const float* B1t = cst + 2304; const float* WC = cst + 4608;
    float a0f[3][3], b1f[3][3], wc[3];
    #pragma unroll
    for (int g = 0; g < 3; ++g) {
        wc[g] = WC[g * H + t];
        #pragma unroll
        for (int c = 0; c < 3; ++c) {
            a0f[g][c] = A0t[(g * 3 + c) * H + t];
            b1f[g][c] = B1t[(g * 3 + c) * H + t];
        }
    }

    for (int i = t; i < BT * TT; i += 256) {
        int b = i >> 7, tt = i & 127;
        float2 v = *(const float2*)(x + ((size_t)(r0 + b) * TT + tt) * 2);
        xm[b][tt] = v.x;
        int c = (int)v.y; c = c < 0 ? 0 : (c > 2 ? 2 : c);
        xcl[b][tt] = (unsigned char)c;
    }
    #pragma unroll
    for (int b = 0; b < BT + 1; ++b) { h0s[b][t] = 0.f; h1s[b][t] = 0.f; rh0[b][t] = 0.f; rh1[b][t] = 0.f; }
    __syncthreads();

    const v2f vz2 = {0.f, 0.f};

    for (int step = 0; step < TT; ++step) {
        float zv[BT], h0v[BT], z1v[BT], h1v[BT], ahWv[BT], mm[BT];
        int cc[BT];
        #pragma unroll
        for (int b = 0; b < BT; ++b) { cc[b] = xcl[b][step]; mm[b] = xm[b][step]; }

        // ===== Phase A: h0 @ {Uz0,Ur0}^T  (weight ring d16, h dbuf) =====
        v2f az2[BT], ar2[BT];
        #pragma unroll
        for (int b = 0; b < BT; ++b) { az2[b] = vz2; ar2[b] = vz2; }
        {
            const float4* pA = wbA + t;           // stride 512 f4 per k4
            float4 wz[16], wr[16];
            #pragma unroll
            for (int i = 0; i < 16; ++i) { wz[i] = pA[i * 512]; wr[i] = pA[i * 512 + 256]; }
            float4 ha[BT], hb[BT];
            #pragma unroll
            for (int b = 0; b < BT; ++b) ha[b] = *(const float4*)&h0s[b][0];
            for (int kb = 0; kb < 4; ++kb) {
                #pragma unroll
                for (int j = 0; j < 16; ++j) {
                    const int k4 = kb * 16 + j;
                    float4 W1 = wz[j], W2 = wr[j];
                    wz[j] = pA[(k4 + 16) * 512];           // over-read -> wbH (benign)
                    wr[j] = pA[(k4 + 16) * 512 + 256];
                    v2f w1l = {W1.x, W1.y}, w1h = {W1.z, W1.w};
                    v2f w2l = {W2.x, W2.y}, w2h = {W2.z, W2.w};
                    if ((j & 1) == 0) {
                        #pragma unroll
                        for (int b = 0; b < BT; ++b) hb[b] = *(const float4*)&h0s[b][(k4 + 1) * 4];
                        #pragma unroll
                        for (int b = 0; b < BT; ++b) {
                            v2f alo = {ha[b].x, ha[b].y}, ahi = {ha[b].z, ha[b].w};
                            az2[b] += alo * w1l + ahi * w1h;
                            ar2[b] += alo * w2l + ahi * w2h;
                        }
                    } else {
                        #pragma unroll
                        for (int b = 0; b < BT; ++b) ha[b] = *(const float4*)&h0s[b][(k4 + 1) * 4];
                        #pragma unroll
                        for (int b = 0; b < BT; ++b) {
                            v2f alo = {hb[b].x, hb[b].y}, ahi = {hb[b].z, hb[b].w};
                            az2[b] += alo * w1l + ahi * w1h;
                            ar2[b] += alo * w2l + ahi * w2h;
                        }
                    }
                }
            }
        }
        #pragma unroll
        for (int b = 0; b < BT; ++b) {
            int c = cc[b];
            float z  = sigf(az2[b][0] + az2[b][1] + mm[b] * wc[0] + a0f[0][c]);
            float rg = sigf(ar2[b][0] + ar2[b][1] + mm[b] * wc[1] + a0f[1][c]);
            h0v[b] = h0s[b][t]; zv[b] = z;
            rh0[b][t] = rg * h0v[b];
        }
        __syncthreads();

        // ===== Phase B: (r∘h0) @ Uh0^T  (ring d16, h dbuf) =====
        v2f ab2[BT];
        #pragma unroll
        for (int b = 0; b < BT; ++b) ab2[b] = vz2;
        {
            const float4* pB = wbH + t;           // stride 256
            float4 wh[16];
            #pragma unroll
            for (int i = 0; i < 16; ++i) wh[i] = pB[i * 256];
            float4 ha[BT], hb[BT];
            #pragma unroll
            for (int b = 0; b < BT; ++b) ha[b] = *(const float4*)&rh0[b][0];
            for (int kb = 0; kb < 4; ++kb) {
                #pragma unroll
                for (int j = 0; j < 16; ++j) {
                    const int k4 = kb * 16 + j;
                    float4 W1 = wh[j];
                    wh[j] = pB[(k4 + 16) * 256];           // over-read -> wbC (benign)
                    v2f w1l = {W1.x, W1.y}, w1h = {W1.z, W1.w};
                    if ((j & 1) == 0) {
                        #pragma unroll
                        for (int b = 0; b < BT; ++b) hb[b] = *(const float4*)&rh0[b][(k4 + 1) * 4];
                        #pragma unroll
                        for (int b = 0; b < BT; ++b) {
                            v2f alo = {ha[b].x, ha[b].y}, ahi = {ha[b].z, ha[b].w};
                            ab2[b] += alo * w1l + ahi * w1h;
                        }
                    } else {
                        #pragma unroll
                        for (int b = 0; b < BT; ++b) ha[b] = *(const float4*)&rh0[b][(k4 + 1) * 4];
                        #pragma unroll
                        for (int b = 0; b < BT; ++b) {
                            v2f alo = {hb[b].x, hb[b].y}, ahi = {hb[b].z, hb[b].w};
                            ab2[b] += alo * w1l + ahi * w1h;
                        }
                    }
                }
            }
        }
        #pragma unroll
        for (int b = 0; b < BT; ++b) {
            int c = cc[b];
            float ht = tanh_fast(ab2[b][0] + ab2[b][1] + mm[b] * wc[2] + a0f[2][c]);
            h0s[b][t] = (1.f - zv[b]) * h0v[b] + zv[b] * ht;
        }
        __syncthreads();

        // ===== Phase C: h0n@{Wz1,Wr1,Wh1}^T + h1@{Uz1,Ur1}^T (ring d8, h dbuf) =====
        v2f cz2[BT], cr2[BT], cw2[BT];
        #pragma unroll
        for (int b = 0; b < BT; ++b) { cz2[b] = vz2; cr2[b] = vz2; cw2[b] = vz2; }
        {
            const float4* pC = wbC + t;           // stride 1280 f4 per k4
            float4 qz[8], qr[8], qw[8], qu[8], qv[8];
            #pragma unroll
            for (int i = 0; i < 8; ++i) {
                qz[i] = pC[i * 1280];        qr[i] = pC[i * 1280 + 256];
                qw[i] = pC[i * 1280 + 512];  qu[i] = pC[i * 1280 + 768];
                qv[i] = pC[i * 1280 + 1024];
            }
            float4 c0a[BT], c0b[BT], c1a[BT], c1b[BT];
            #pragma unroll
            for (int b = 0; b < BT; ++b) {
                c0a[b] = *(const float4*)&h0s[b][0];
                c1a[b] = *(const float4*)&h1s[b][0];
            }
            for (int kb = 0; kb < 8; ++kb) {
                #pragma unroll
                for (int j = 0; j < 8; ++j) {
                    const int k4 = kb * 8 + j;
                    float4 W1 = qz[j], W2 = qr[j], W3 = qw[j], W4 = qu[j], W5 = qv[j];
                    int base = (k4 + 8) * 1280;            // over-read -> wbD (benign)
                    qz[j] = pC[base];        qr[j] = pC[base + 256];
                    qw[j] = pC[base + 512];  qu[j] = pC[base + 768];
                    qv[j] = pC[base + 1024];
                    v2f w1l = {W1.x, W1.y}, w1h = {W1.z, W1.w};
                    v2f w2l = {W2.x, W2.y}, w2h = {W2.z, W2.w};
                    v2f w3l = {W3.x, W3.y}, w3h = {W3.z, W3.w};
                    v2f w4l = {W4.x, W4.y}, w4h = {W4.z, W4.w};
                    v2f w5l = {W5.x, W5.y}, w5h = {W5.z, W5.w};
                    if ((j & 1) == 0) {
                        #pragma unroll
                        for (int b = 0; b < BT; ++b) {
                            c0b[b] = *(const float4*)&h0s[b][(k4 + 1) * 4];
                            c1b[b] = *(const float4*)&h1s[b][(k4 + 1) * 4];
                        }
                        #pragma unroll
                        for (int b = 0; b < BT; ++b) {
                            v2f alo = {c0a[b].x, c0a[b].y}, ahi = {c0a[b].z, c0a[b].w};
                            v2f vlo = {c1a[b].x, c1a[b].y}, vhi = {c1a[b].z, c1a[b].w};
                            cz2[b] += alo * w1l + ahi * w1h + vlo * w4l + vhi * w4h;
                            cr2[b] += alo * w2l + ahi * w2h + vlo * w5l + vhi * w5h;
                            cw2[b] += alo * w3l + ahi * w3h;
                        }
                    } else {
                        #pragma unroll
                        for (int b = 0; b < BT; ++b) {
                            c0a[b] = *(const float4*)&h0s[b][(k4 + 1) * 4];
                            c1a[b] = *(const float4*)&h1s[b][(k4 + 1) * 4];
                        }
                        #pragma unroll
                        for (int b = 0; b < BT; ++b) {
                            v2f alo = {c0b[b].x, c0b[b].y}, ahi = {c0b[b].z, c0b[b].w};
                            v2f vlo = {c1b[b].x, c1b[b].y}, vhi = {c1b[b].z, c1b[b].w};
                            cz2[b] += alo * w1l + ahi * w1h + vlo * w4l + vhi * w4h;
                            cr2[b] += alo * w2l + ahi * w2h + vlo * w5l + vhi * w5h;
                            cw2[b] += alo * w3l + ahi * w3h;
                        }
                    }
                }
            }
        }
        #pragma unroll
        for (int b = 0; b < BT; ++b) {
            int c = cc[b];
            float z1 = sigf(cz2[b][0] + cz2[b][1] + b1f[0][c]);
            float r1 = sigf(cr2[b][0] + cr2[b][1] + b1f[1][c]);
            ahWv[b] = cw2[b][0] + cw2[b][1];
            h1v[b] = h1s[b][t]; z1v[b] = z1;
            rh1[b][t] = r1 * h1v[b];
        }
        __syncthreads();

        // ===== Phase D: (r1∘h1) @ Uh1^T  (ring d4, h dbuf) =====
        v2f ad2[BT];
        #pragma unroll
        for (int b = 0; b < BT; ++b) ad2[b] = vz2;
        {
            const float4* pD = wbD + t;           // stride 256
            float4 wh[4];
            #pragma unroll
            for (int i = 0; i < 4; ++i) wh[i] = pD[i * 256];
            float4 ha[BT], hb[BT];
            #pragma unroll
            for (int b = 0; b < BT; ++b) ha[b] = *(const float4*)&rh1[b][0];
            for (int kb = 0; kb < 16; ++kb) {
                #pragma unroll
                for (int j = 0; j < 4; ++j) {
                    const int k4 = kb * 4 + j;
                    float4 W1 = wh[j];
                    wh[j] = pD[(k4 + 4) * 256];            // over-read -> cst tail (benign)
                    v2f w1l = {W1.x, W1.y}, w1h = {W1.z, W1.w};
                    if ((j & 1) == 0) {
                        #pragma unroll
                        for (int b = 0; b < BT; ++b) hb[b] = *(const float4*)&rh1[b][(k4 + 1) * 4];
                        #pragma unroll
                        for (int b = 0; b < BT; ++b) {
                            v2f alo = {ha[b].x, ha[b].y}, ahi = {ha[b].z, ha[b].w};
                            ad2[b] += alo * w1l + ahi * w1h;
                        }
                    } else {
                        #pragma unroll
                        for (int b = 0; b < BT; ++b) ha[b] = *(const float4*)&rh1[b][(k4 + 1) * 4];
                        #pragma unroll
                        for (int b = 0; b < BT; ++b) {
                            v2f alo = {hb[b].x, hb[b].y}, ahi = {hb[b].z, hb[b].w};
                            ad2[b] += alo * w1l + ahi * w1h;
                        }
                    }
                }
            }
        }
        #pragma unroll
        for (int b = 0; b < BT; ++b) {
            int c = cc[b];
            float ht1 = tanh_fast(ahWv[b] + ad2[b][0] + ad2[b][1] + b1f[2][c]);
            h1s[b][t] = (1.f - z1v[b]) * h1v[b] + z1v[b] * ht1;
        }
        __syncthreads();
    }

    // ---- epilogue: out = h1 @ fc_w^T + fc_b
    if (t < BT * PP) {
        int b = t / PP, p = t - b * PP;
        float s = fcb[p];
        for (int h = 0; h < H; ++h) s += h1s[b][h] * fcw[p * H + h];
        out[(size_t)(r0 + b) * PP + p] = s;
    }
}

extern "C" void kernel_launch(void* const* d_in, const int* in_sizes, int n_in,
                              void* d_out, int out_size, void* d_ws, size_t ws_size,
                              hipStream_t stream)
{
    const float* x   = (const float*)d_in[0];
    const float* emb = (const float*)d_in[1];
    const float* Wz0 = (const float*)d_in[2];  const float* Wr0 = (const float*)d_in[3];
    const float* Wh0 = (const float*)d_in[4];
    const float* Uz0 = (const float*)d_in[5];  const float* Ur0 = (const float*)d_in[6];
    const float* Uh0 = (const float*)d_in[7];
    const float* Vw0 = (const float*)d_in[8];  const float* Vb0 = (const float*)d_in[9];
    const float* lz0 = (const float*)d_in[10]; const float* lr0 = (const float*)d_in[11];
    const float* lh0 = (const float*)d_in[12];
    const float* Wz1 = (const float*)d_in[13]; const float* Wr1 = (const float*)d_in[14];
    const float* Wh1 = (const float*)d_in[15];
    const float* Uz1 = (const float*)d_in[16]; const float* Ur1 = (const float*)d_in[17];
    const float* Uh1 = (const float*)d_in[18];
    const float* Vw1 = (const float*)d_in[19]; const float* Vb1 = (const float*)d_in[20];
    const float* lz1 = (const float*)d_in[21]; const float* lr1 = (const float*)d_in[22];
    const float* lh1 = (const float*)d_in[23];
    const float* fcw = (const float*)d_in[24]; const float* fcb = (const float*)d_in[25];

    float*  ws  = (float*)d_ws;
    float4* wbA = (float4*)ws;                         // f4 [0, 32768)
    float4* wbH = (float4*)(ws + 131072);              // f4 [32768, 49152)
    float4* wbC = (float4*)(ws + 196608);              // f4 [49152, 131072)
    float4* wbD = (float4*)(ws + 524288);              // f4 [131072, 147456)
    float*  cst = ws + 589824;                         // 5376 floats (absorbs D over-read)

    hipLaunchKernelGGL(pack_weights, dim3(576), dim3(256), 0, stream,
                       Uz0, Ur0, Uh0, Wz1, Wr1, Wh1, Uz1, Ur1, Uh1, wbA, wbH, wbC, wbD);
    hipLaunchKernelGGL(pack_consts, dim3(1), dim3(256), 0, stream,
                       Wz0, Wr0, Wh0, Vw0, Vb0, lz0, lr0, lh0,
                       Wz1, Wr1, Wh1, Vw1, Vb1, lz1, lr1, lh1, emb, cst);
    hipLaunchKernelGGL(trs_scan, dim3(2048 / BT), dim3(256), 0, stream,
                       x, wbA, wbH, wbC, wbD, cst, fcw, fcb, (float*)d_out);
}

// Round 14
// 6943.078 us; speedup vs baseline: 1.4714x; 1.4714x over previous
//
#include <hip/hip_runtime.h>
#include <math.h>

#define H   256
#define TT  128
#define BT  8     // batch rows per block; grid = 256 = 1 block/CU (proven clean)
#define PP  6

typedef float v2f __attribute__((ext_vector_type(2)));

__device__ __forceinline__ float sigf(float x) { return 1.0f / (1.0f + __expf(-x)); }
__device__ __forceinline__ float tanh_fast(float x) {
    float t = __expf(-2.0f * fabsf(x));
    float r = (1.0f - t) / (1.0f + t);
    return copysignf(r, x);
}

// ---------------- pack weights (R2-verified layout, unchanged) --------------
// wbA[(k4*2+g)*256+t] = {Uz0,Ur0}[t][4k4..+3]
// wbH[k4*256+t]       = Uh0[t][4k4..+3]
// wbC[(k4*5+g)*256+t] = g=0..2: {Wz1,Wr1,Wh1}[t][4k4..+3] (ld 264, h0n cols)
//                       g=3,4 : {Uz1,Ur1}[t][4k4..+3]      (ld 256, h1 cols)
// wbD[k4*256+t]       = Uh1[t][4k4..+3]
__global__ void pack_weights(const float* __restrict__ Uz0, const float* __restrict__ Ur0, const float* __restrict__ Uh0,
                             const float* __restrict__ Wz1, const float* __restrict__ Wr1, const float* __restrict__ Wh1,
                             const float* __restrict__ Uz1, const float* __restrict__ Ur1, const float* __restrict__ Uh1,
                             float4* __restrict__ wbA, float4* __restrict__ wbH,
                             float4* __restrict__ wbC, float4* __restrict__ wbD)
{
    int idx = blockIdx.x * 256 + threadIdx.x;   // 0..147455
    if (idx < 32768) {
        int k4 = idx >> 9; int g = (idx >> 8) & 1; int t = idx & 255;
        const float* p = (g ? Ur0 : Uz0) + t * H + k4 * 4;
        wbA[idx] = make_float4(p[0], p[1], p[2], p[3]);
    } else if (idx < 49152) {
        int i = idx - 32768;
        int k4 = i >> 8, t = i & 255;
        const float* p = Uh0 + t * H + k4 * 4;
        wbH[i] = make_float4(p[0], p[1], p[2], p[3]);
    } else if (idx < 131072) {
        int i = idx - 49152;                       // 0..81919
        int k4 = i / 1280; int rem = i - k4 * 1280; int g = rem >> 8; int t = rem & 255;
        const float* p;
        if (g < 3) { const float* W = (g == 0) ? Wz1 : ((g == 1) ? Wr1 : Wh1); p = W + t * 264 + k4 * 4; }
        else       { const float* U = (g == 3) ? Uz1 : Ur1;                    p = U + t * H   + k4 * 4; }
        wbC[i] = make_float4(p[0], p[1], p[2], p[3]);
    } else if (idx < 147456) {
        int i = idx - 131072;
        int k4 = i >> 8, t = i & 255;
        const float* p = Uh1 + t * H + k4 * 4;
        wbD[i] = make_float4(p[0], p[1], p[2], p[3]);
    }
}

// ---- constants, folded (R5-verified, unchanged) ----------------------------
__global__ void pack_consts(const float* __restrict__ Wz0, const float* __restrict__ Wr0, const float* __restrict__ Wh0,
                            const float* __restrict__ Vw0, const float* __restrict__ Vb0,
                            const float* __restrict__ lz0, const float* __restrict__ lr0, const float* __restrict__ lh0,
                            const float* __restrict__ Wz1, const float* __restrict__ Wr1, const float* __restrict__ Wh1,
                            const float* __restrict__ Vw1, const float* __restrict__ Vb1,
                            const float* __restrict__ lz1, const float* __restrict__ lr1, const float* __restrict__ lh1,
                            const float* __restrict__ emb, float* __restrict__ cst)
{
    int t = threadIdx.x;
    float* A0t = cst; float* B1t = cst + 2304; float* WC = cst + 4608;
    const float* W0s[3] = {Wz0, Wr0, Wh0};
    const float* W1s[3] = {Wz1, Wr1, Wh1};
    const float* ls0[3] = {lz0, lr0, lh0};
    const float* ls1[3] = {lz1, lr1, lh1};
    for (int g = 0; g < 3; ++g) {
        WC[g * H + t] = W0s[g][t * 9];
        float L0g = 0.05f + 0.45f * sigf(ls0[g][t]);
        float L1g = 0.05f + 0.45f * sigf(ls1[g][t]);
        for (int c = 0; c < 3; ++c) {
            float s0 = 0.f, s1 = 0.f, i0 = Vb0[t], i1 = Vb1[t];
            for (int e = 0; e < 8; ++e) {
                float em = emb[c * 8 + e];
                s0 += W0s[g][t * 9 + 1 + e]     * em;
                s1 += W1s[g][t * 264 + 256 + e] * em;
                i0 += Vw0[t * 8 + e] * em;
                i1 += Vw1[t * 8 + e] * em;
            }
            A0t[(g * 3 + c) * H + t] = s0 + L0g * i0;
            B1t[(g * 3 + c) * H + t] = s1 + L1g * i1;
        }
    }
}

// -------- persistent scan: R12 frame, rings A8 / B16 / C4 / D8 --------------
// 256 thr, thread t owns hidden unit t for all 8 rows, grid 256 (1 block/CU).
__global__ __launch_bounds__(256, 1) void trs_scan(
    const float* __restrict__ x,
    const float4* __restrict__ wbA, const float4* __restrict__ wbH,
    const float4* __restrict__ wbC, const float4* __restrict__ wbD,
    const float* __restrict__ cst, const float* __restrict__ fcw, const float* __restrict__ fcb,
    float* __restrict__ out)
{
    // +1 padding row: k4=63 h-prefetch over-reads stay in-bounds
    __shared__ __align__(16) float h0s[BT + 1][H];
    __shared__ __align__(16) float h1s[BT + 1][H];
    __shared__ __align__(16) float rh0[BT + 1][H];
    __shared__ __align__(16) float rh1[BT + 1][H];
    __shared__ float xm[BT][TT];
    __shared__ unsigned char xcl[BT][TT];

    const int t  = threadIdx.x;
    const int r0 = blockIdx.x * BT;

    const float* A0t = cst; const float* B1t = cst + 2304; const float* WC = cst + 4608;
    float a0f[3][3], b1f[3][3], wc[3];
    #pragma unroll
    for (int g = 0; g < 3; ++g) {
        wc[g] = WC[g * H + t];
        #pragma unroll
        for (int c = 0; c < 3; ++c) {
            a0f[g][c] = A0t[(g * 3 + c) * H + t];
            b1f[g][c] = B1t[(g * 3 + c) * H + t];
        }
    }

    for (int i = t; i < BT * TT; i += 256) {
        int b = i >> 7, tt = i & 127;
        float2 v = *(const float2*)(x + ((size_t)(r0 + b) * TT + tt) * 2);
        xm[b][tt] = v.x;
        int c = (int)v.y; c = c < 0 ? 0 : (c > 2 ? 2 : c);
        xcl[b][tt] = (unsigned char)c;
    }
    #pragma unroll
    for (int b = 0; b < BT + 1; ++b) { h0s[b][t] = 0.f; h1s[b][t] = 0.f; rh0[b][t] = 0.f; rh1[b][t] = 0.f; }
    __syncthreads();

    const v2f vz2 = {0.f, 0.f};

    for (int step = 0; step < TT; ++step) {
        float zv[BT], h0v[BT], z1v[BT], h1v[BT], ahWv[BT], mm[BT];
        int cc[BT];
        #pragma unroll
        for (int b = 0; b < BT; ++b) { cc[b] = xcl[b][step]; mm[b] = xm[b][step]; }

        // ===== Phase A: h0 @ {Uz0,Ur0}^T  (weight ring d8, h dbuf) =====
        v2f az2[BT], ar2[BT];
        #pragma unroll
        for (int b = 0; b < BT; ++b) { az2[b] = vz2; ar2[b] = vz2; }
        {
            const float4* pA = wbA + t;           // stride 512 f4 per k4
            float4 wz[8], wr[8];
            #pragma unroll
            for (int i = 0; i < 8; ++i) { wz[i] = pA[i * 512]; wr[i] = pA[i * 512 + 256]; }
            float4 ha[BT], hb[BT];
            #pragma unroll
            for (int b = 0; b < BT; ++b) ha[b] = *(const float4*)&h0s[b][0];
            for (int kb = 0; kb < 8; ++kb) {
                #pragma unroll
                for (int j = 0; j < 8; ++j) {
                    const int k4 = kb * 8 + j;
                    float4 W1 = wz[j], W2 = wr[j];
                    wz[j] = pA[(k4 + 8) * 512];            // over-read -> wbH (benign)
                    wr[j] = pA[(k4 + 8) * 512 + 256];
                    v2f w1l = {W1.x, W1.y}, w1h = {W1.z, W1.w};
                    v2f w2l = {W2.x, W2.y}, w2h = {W2.z, W2.w};
                    if ((j & 1) == 0) {
                        #pragma unroll
                        for (int b = 0; b < BT; ++b) hb[b] = *(const float4*)&h0s[b][(k4 + 1) * 4];
                        #pragma unroll
                        for (int b = 0; b < BT; ++b) {
                            v2f alo = {ha[b].x, ha[b].y}, ahi = {ha[b].z, ha[b].w};
                            az2[b] += alo * w1l + ahi * w1h;
                            ar2[b] += alo * w2l + ahi * w2h;
                        }
                    } else {
                        #pragma unroll
                        for (int b = 0; b < BT; ++b) ha[b] = *(const float4*)&h0s[b][(k4 + 1) * 4];
                        #pragma unroll
                        for (int b = 0; b < BT; ++b) {
                            v2f alo = {hb[b].x, hb[b].y}, ahi = {hb[b].z, hb[b].w};
                            az2[b] += alo * w1l + ahi * w1h;
                            ar2[b] += alo * w2l + ahi * w2h;
                        }
                    }
                }
            }
        }
        #pragma unroll
        for (int b = 0; b < BT; ++b) {
            int c = cc[b];
            float z  = sigf(az2[b][0] + az2[b][1] + mm[b] * wc[0] + a0f[0][c]);
            float rg = sigf(ar2[b][0] + ar2[b][1] + mm[b] * wc[1] + a0f[1][c]);
            h0v[b] = h0s[b][t]; zv[b] = z;
            rh0[b][t] = rg * h0v[b];
        }
        __syncthreads();

        // ===== Phase B: (r∘h0) @ Uh0^T  (ring d16, h dbuf) =====
        v2f ab2[BT];
        #pragma unroll
        for (int b = 0; b < BT; ++b) ab2[b] = vz2;
        {
            const float4* pB = wbH + t;           // stride 256
            float4 wh[16];
            #pragma unroll
            for (int i = 0; i < 16; ++i) wh[i] = pB[i * 256];
            float4 ha[BT], hb[BT];
            #pragma unroll
            for (int b = 0; b < BT; ++b) ha[b] = *(const float4*)&rh0[b][0];
            for (int kb = 0; kb < 4; ++kb) {
                #pragma unroll
                for (int j = 0; j < 16; ++j) {
                    const int k4 = kb * 16 + j;
                    float4 W1 = wh[j];
                    wh[j] = pB[(k4 + 16) * 256];           // over-read -> wbC (benign)
                    v2f w1l = {W1.x, W1.y}, w1h = {W1.z, W1.w};
                    if ((j & 1) == 0) {
                        #pragma unroll
                        for (int b = 0; b < BT; ++b) hb[b] = *(const float4*)&rh0[b][(k4 + 1) * 4];
                        #pragma unroll
                        for (int b = 0; b < BT; ++b) {
                            v2f alo = {ha[b].x, ha[b].y}, ahi = {ha[b].z, ha[b].w};
                            ab2[b] += alo * w1l + ahi * w1h;
                        }
                    } else {
                        #pragma unroll
                        for (int b = 0; b < BT; ++b) ha[b] = *(const float4*)&rh0[b][(k4 + 1) * 4];
                        #pragma unroll
                        for (int b = 0; b < BT; ++b) {
                            v2f alo = {hb[b].x, hb[b].y}, ahi = {hb[b].z, hb[b].w};
                            ab2[b] += alo * w1l + ahi * w1h;
                        }
                    }
                }
            }
        }
        #pragma unroll
        for (int b = 0; b < BT; ++b) {
            int c = cc[b];
            float ht = tanh_fast(ab2[b][0] + ab2[b][1] + mm[b] * wc[2] + a0f[2][c]);
            h0s[b][t] = (1.f - zv[b]) * h0v[b] + zv[b] * ht;
        }
        __syncthreads();

        // ===== Phase C: h0n@{Wz1,Wr1,Wh1}^T + h1@{Uz1,Ur1}^T (ring d4, h dbuf) =====
        v2f cz2[BT], cr2[BT], cw2[BT];
        #pragma unroll
        for (int b = 0; b < BT; ++b) { cz2[b] = vz2; cr2[b] = vz2; cw2[b] = vz2; }
        {
            const float4* pC = wbC + t;           // stride 1280 f4 per k4
            float4 qz[4], qr[4], qw[4], qu[4], qv[4];
            #pragma unroll
            for (int i = 0; i < 4; ++i) {
                qz[i] = pC[i * 1280];        qr[i] = pC[i * 1280 + 256];
                qw[i] = pC[i * 1280 + 512];  qu[i] = pC[i * 1280 + 768];
                qv[i] = pC[i * 1280 + 1024];
            }
            float4 c0a[BT], c0b[BT], c1a[BT], c1b[BT];
            #pragma unroll
            for (int b = 0; b < BT; ++b) {
                c0a[b] = *(const float4*)&h0s[b][0];
                c1a[b] = *(const float4*)&h1s[b][0];
            }
            for (int kb = 0; kb < 16; ++kb) {
                #pragma unroll
                for (int j = 0; j < 4; ++j) {
                    const int k4 = kb * 4 + j;
                    float4 W1 = qz[j], W2 = qr[j], W3 = qw[j], W4 = qu[j], W5 = qv[j];
                    int base = (k4 + 4) * 1280;            // over-read -> wbD (benign)
                    qz[j] = pC[base];        qr[j] = pC[base + 256];
                    qw[j] = pC[base + 512];  qu[j] = pC[base + 768];
                    qv[j] = pC[base + 1024];
                    v2f w1l = {W1.x, W1.y}, w1h = {W1.z, W1.w};
                    v2f w2l = {W2.x, W2.y}, w2h = {W2.z, W2.w};
                    v2f w3l = {W3.x, W3.y}, w3h = {W3.z, W3.w};
                    v2f w4l = {W4.x, W4.y}, w4h = {W4.z, W4.w};
                    v2f w5l = {W5.x, W5.y}, w5h = {W5.z, W5.w};
                    if ((j & 1) == 0) {
                        #pragma unroll
                        for (int b = 0; b < BT; ++b) {
                            c0b[b] = *(const float4*)&h0s[b][(k4 + 1) * 4];
                            c1b[b] = *(const float4*)&h1s[b][(k4 + 1) * 4];
                        }
                        #pragma unroll
                        for (int b = 0; b < BT; ++b) {
                            v2f alo = {c0a[b].x, c0a[b].y}, ahi = {c0a[b].z, c0a[b].w};
                            v2f vlo = {c1a[b].x, c1a[b].y}, vhi = {c1a[b].z, c1a[b].w};
                            cz2[b] += alo * w1l + ahi * w1h + vlo * w4l + vhi * w4h;
                            cr2[b] += alo * w2l + ahi * w2h + vlo * w5l + vhi * w5h;
                            cw2[b] += alo * w3l + ahi * w3h;
                        }
                    } else {
                        #pragma unroll
                        for (int b = 0; b < BT; ++b) {
                            c0a[b] = *(const float4*)&h0s[b][(k4 + 1) * 4];
                            c1a[b] = *(const float4*)&h1s[b][(k4 + 1) * 4];
                        }
                        #pragma unroll
                        for (int b = 0; b < BT; ++b) {
                            v2f alo = {c0b[b].x, c0b[b].y}, ahi = {c0b[b].z, c0b[b].w};
                            v2f vlo = {c1b[b].x, c1b[b].y}, vhi = {c1b[b].z, c1b[b].w};
                            cz2[b] += alo * w1l + ahi * w1h + vlo * w4l + vhi * w4h;
                            cr2[b] += alo * w2l + ahi * w2h + vlo * w5l + vhi * w5h;
                            cw2[b] += alo * w3l + ahi * w3h;
                        }
                    }
                }
            }
        }
        #pragma unroll
        for (int b = 0; b < BT; ++b) {
            int c = cc[b];
            float z1 = sigf(cz2[b][0] + cz2[b][1] + b1f[0][c]);
            float r1 = sigf(cr2[b][0] + cr2[b][1] + b1f[1][c]);
            ahWv[b] = cw2[b][0] + cw2[b][1];
            h1v[b] = h1s[b][t]; z1v[b] = z1;
            rh1[b][t] = r1 * h1v[b];
        }
        __syncthreads();

        // ===== Phase D: (r1∘h1) @ Uh1^T  (ring d8, h dbuf) =====
        v2f ad2[BT];
        #pragma unroll
        for (int b = 0; b < BT; ++b) ad2[b] = vz2;
        {
            const float4* pD = wbD + t;           // stride 256
            float4 wh[8];
            #pragma unroll
            for (int i = 0; i < 8; ++i) wh[i] = pD[i * 256];
            float4 ha[BT], hb[BT];
            #pragma unroll
            for (int b = 0; b < BT; ++b) ha[b] = *(const float4*)&rh1[b][0];
            for (int kb = 0; kb < 8; ++kb) {
                #pragma unroll
                for (int j = 0; j < 8; ++j) {
                    const int k4 = kb * 8 + j;
                    float4 W1 = wh[j];
                    wh[j] = pD[(k4 + 8) * 256];            // over-read -> ws pad (benign)
                    v2f w1l = {W1.x, W1.y}, w1h = {W1.z, W1.w};
                    if ((j & 1) == 0) {
                        #pragma unroll
                        for (int b = 0; b < BT; ++b) hb[b] = *(const float4*)&rh1[b][(k4 + 1) * 4];
                        #pragma unroll
                        for (int b = 0; b < BT; ++b) {
                            v2f alo = {ha[b].x, ha[b].y}, ahi = {ha[b].z, ha[b].w};
                            ad2[b] += alo * w1l + ahi * w1h;
                        }
                    } else {
                        #pragma unroll
                        for (int b = 0; b < BT; ++b) ha[b] = *(const float4*)&rh1[b][(k4 + 1) * 4];
                        #pragma unroll
                        for (int b = 0; b < BT; ++b) {
                            v2f alo = {hb[b].x, hb[b].y}, ahi = {hb[b].z, hb[b].w};
                            ad2[b] += alo * w1l + ahi * w1h;
                        }
                    }
                }
            }
        }
        #pragma unroll
        for (int b = 0; b < BT; ++b) {
            int c = cc[b];
            float ht1 = tanh_fast(ahWv[b] + ad2[b][0] + ad2[b][1] + b1f[2][c]);
            h1s[b][t] = (1.f - z1v[b]) * h1v[b] + z1v[b] * ht1;
        }
        __syncthreads();
    }

    // ---- epilogue: out = h1 @ fc_w^T + fc_b
    if (t < BT * PP) {
        int b = t / PP, p = t - b * PP;
        float s = fcb[p];
        for (int h = 0; h < H; ++h) s += h1s[b][h] * fcw[p * H + h];
        out[(size_t)(r0 + b) * PP + p] = s;
    }
}

extern "C" void kernel_launch(void* const* d_in, const int* in_sizes, int n_in,
                              void* d_out, int out_size, void* d_ws, size_t ws_size,
                              hipStream_t stream)
{
    const float* x   = (const float*)d_in[0];
    const float* emb = (const float*)d_in[1];
    const float* Wz0 = (const float*)d_in[2];  const float* Wr0 = (const float*)d_in[3];
    const float* Wh0 = (const float*)d_in[4];
    const float* Uz0 = (const float*)d_in[5];  const float* Ur0 = (const float*)d_in[6];
    const float* Uh0 = (const float*)d_in[7];
    const float* Vw0 = (const float*)d_in[8];  const float* Vb0 = (const float*)d_in[9];
    const float* lz0 = (const float*)d_in[10]; const float* lr0 = (const float*)d_in[11];
    const float* lh0 = (const float*)d_in[12];
    const float* Wz1 = (const float*)d_in[13]; const float* Wr1 = (const float*)d_in[14];
    const float* Wh1 = (const float*)d_in[15];
    const float* Uz1 = (const float*)d_in[16]; const float* Ur1 = (const float*)d_in[17];
    const float* Uh1 = (const float*)d_in[18];
    const float* Vw1 = (const float*)d_in[19]; const float* Vb1 = (const float*)d_in[20];
    const float* lz1 = (const float*)d_in[21]; const float* lr1 = (const float*)d_in[22];
    const float* lh1 = (const float*)d_in[23];
    const float* fcw = (const float*)d_in[24]; const float* fcb = (const float*)d_in[25];

    float*  ws  = (float*)d_ws;
    float4* wbA = (float4*)ws;                         // f4 [0, 32768)
    float4* wbH = (float4*)(ws + 131072);              // f4 [32768, 49152)
    float4* wbC = (float4*)(ws + 196608);              // f4 [49152, 131072)
    float4* wbD = (float4*)(ws + 524288);              // f4 [131072, 147456)
    // pad [589824, 598016): absorbs phase-D d8 over-reads (2047 f4 max)
    float*  cst = ws + 598016;                         // 5376 floats

    hipLaunchKernelGGL(pack_weights, dim3(576), dim3(256), 0, stream,
                       Uz0, Ur0, Uh0, Wz1, Wr1, Wh1, Uz1, Ur1, Uh1, wbA, wbH, wbC, wbD);
    hipLaunchKernelGGL(pack_consts, dim3(1), dim3(256), 0, stream,
                       Wz0, Wr0, Wh0, Vw0, Vb0, lz0, lr0, lh0,
                       Wz1, Wr1, Wh1, Vw1, Vb1, lz1, lr1, lh1, emb, cst);
    hipLaunchKernelGGL(trs_scan, dim3(2048 / BT), dim3(256), 0, stream,
                       x, wbA, wbH, wbC, wbD, cst, fcw, fcb, (float*)d_out);
}